// Round 7
// baseline (34.744 us; speedup 1.0000x reference)
//
#include <hip/hip_runtime.h>

namespace {

constexpr int NSC  = 512;   // subcarriers
constexpr int CP   = 7;     // cyclic prefix
constexpr int NTOT = 519;   // N + CP

// pad every 16 slots by 1 (works for float2 and float4 granularity)
__device__ __forceinline__ int p2(int x) { return x + (x >> 4); }
__device__ __forceinline__ int p4(int x) { return x + (x >> 4); }

struct cf { float x, y; };
__device__ __forceinline__ cf cadd(cf a, cf b) { return {a.x + b.x, a.y + b.y}; }
__device__ __forceinline__ cf csub(cf a, cf b) { return {a.x - b.x, a.y - b.y}; }
__device__ __forceinline__ cf cmul(cf a, cf b) { return {a.x*b.x - a.y*b.y, a.x*b.y + a.y*b.x}; }
__device__ __forceinline__ cf mni(cf a) { return {a.y, -a.x}; }   // multiply by -i

// natural-order in/out 8-point DFT: out[k] = sum_j in[j] W8^{jk}, W8 = e^{-2pi i/8}
__device__ __forceinline__ void fft8(cf a[8]) {
    const float s = 0.70710678118654752f;
    cf b0 = a[0], b1 = a[4], b2 = a[2], b3 = a[6];
    cf b4 = a[1], b5 = a[5], b6 = a[3], b7 = a[7];
    cf c0 = cadd(b0, b1), c1 = csub(b0, b1);
    cf c2 = cadd(b2, b3), c3 = csub(b2, b3);
    cf c4 = cadd(b4, b5), c5 = csub(b4, b5);
    cf c6 = cadd(b6, b7), c7 = csub(b6, b7);
    cf d0 = cadd(c0, c2), d2 = csub(c0, c2);
    cf d1 = cadd(c1, mni(c3)), d3 = csub(c1, mni(c3));
    cf d4 = cadd(c4, c6), d6 = csub(c4, c6);
    cf d5 = cadd(c5, mni(c7)), d7 = csub(c5, mni(c7));
    cf e5 = { s * (d5.x + d5.y), s * (d5.y - d5.x) };   // W8^1 * d5
    cf e6 = mni(d6);                                     // W8^2 * d6
    cf e7 = { s * (d7.y - d7.x), -s * (d7.x + d7.y) };   // W8^3 * d7
    a[0] = cadd(d0, d4); a[4] = csub(d0, d4);
    a[1] = cadd(d1, e5); a[5] = csub(d1, e5);
    a[2] = cadd(d2, e6); a[6] = csub(d2, e6);
    a[3] = cadd(d3, e7); a[7] = csub(d3, e7);
}

__global__ __launch_bounds__(256, 8) void ofdm_mimo_kernel(
    const float* __restrict__ y_data,
    const float* __restrict__ y_ls,
    const int*   __restrict__ x_idx,
    float*       __restrict__ out,
    int B)
{
    // per-wave FFT workspace (float2, padded). After the FFTs, sb[2..3] are
    // reused IN PLACE (as float4) for the pilot LS estimates:
    //   pil[tt][k] = {rr0.re, rr0.im, rr1.re, rr1.im} at float4-slot p4(k).
    __shared__ cf sb[4][544];

    const int b   = blockIdx.x;
    const int tid = threadIdx.x;
    const int q   = tid >> 6;   // wave id = signal id (0,1: data r0,r1; 2,3: ls r0,r1)
    const int t   = tid & 63;   // lane within the FFT

    // both Y and Y_l scaled by 1/(N*sqrt(pi)) -- 1/sqrt(pi) on the data path
    // folded into the FFT input (solve is linear in Y).
    const float sc = (float)(1.0 / (512.0 * 0.22627416997969522));

    const float W64A  = -6.2831853071795864769f / 64.0f;
    const float W512A = -6.2831853071795864769f / 512.0f;

    // ---- prefetch pilot symbol factors (global loads issued before FFT) ----
    const float lev[4] = {-0.9486832980505138f, -0.31622776601683794f,
                           0.31622776601683794f, 0.9486832980505138f};
    float pxr[2], pxi[2], pinv[2];   // j -> (tt = j, k = tid)
    #pragma unroll
    for (int j = 0; j < 2; ++j) {
        int comb = j + 2 * tid;
        int idx = x_idx[((size_t)(b * 2 + j)) * NSC + comb];
        float xr = lev[idx & 3];
        float xi = lev[(idx >> 2) & 3];
        pxr[j] = xr; pxi[j] = xi;
        pinv[j] = 1.0f / (xr * xr + xi * xi);
    }

    // ---- stage 1: load x[t + 64*n2] (coalesced float2), fft8 over n2 -> k0 ----
    const int r = q & 1;
    const float* srcp = (q < 2) ? y_data : y_ls;
    const float2* xin = (const float2*)(srcp + ((size_t)(b * 2 + r) * NTOT + CP) * 2);

    cf a[8];
    #pragma unroll
    for (int n2 = 0; n2 < 8; ++n2) {
        float2 v = xin[t + 64 * n2];
        a[n2] = { v.x * sc, v.y * sc };
    }
    fft8(a);   // a[k0]

    // twiddle W_64^{n1*k0}: one sincos + power recurrence
    {
        const int n1 = t >> 3;
        float sn, cs;
        __sincosf(W64A * (float)n1, &sn, &cs);
        cf w1 = {cs, sn}, w = w1;
        #pragma unroll
        for (int k0 = 1; k0 < 8; ++k0) {
            a[k0] = cmul(a[k0], w);
            w = cmul(w, w1);
        }
    }
    // T1 write: p2(8t+k0) = 8t + (t>>1) + k0  (8*(t&1)+k0 <= 15, no pad cross)
    {
        cf* pw1 = &sb[q][8 * t + (t >> 1)];
        #pragma unroll
        for (int k0 = 0; k0 < 8; ++k0) pw1[k0] = a[k0];
    }
    __builtin_amdgcn_wave_barrier();

    // ---- stage 2: read A'[n0,n1,k0] over n1; p2(64n1+s2) = 68n1 + s2+(s2>>4) ----
    {
        const int s2 = (t & 7) * 8 + (t >> 3);
        const cf* pr2 = &sb[q][s2 + (s2 >> 4)];
        #pragma unroll
        for (int n1 = 0; n1 < 8; ++n1) a[n1] = pr2[68 * n1];
    }
    __builtin_amdgcn_wave_barrier();
    fft8(a);   // a[k1]

    // twiddle W_512^{n0*(k0+8*k1)} = W512^{n0*k0} * (W64^{n0})^{k1}
    {
        const int n0 = t & 7, k0 = t >> 3;
        float sn, cs, sn2, cs2;
        __sincosf(W512A * (float)(n0 * k0), &sn, &cs);
        __sincosf(W64A * (float)n0, &sn2, &cs2);
        cf w = {cs, sn}, st = {cs2, sn2};
        #pragma unroll
        for (int k1 = 0; k1 < 8; ++k1) {
            a[k1] = cmul(a[k1], w);
            w = cmul(w, st);
        }
    }
    // T2 write: p2(s3+k1) = s3 + (s3>>4) + k1  (s3 mult of 8, k1<=7)
    {
        const int s3 = (t & 7) * 64 + (t >> 3) * 8;
        cf* pw2 = &sb[q][s3 + (s3 >> 4)];
        #pragma unroll
        for (int k1 = 0; k1 < 8; ++k1) pw2[k1] = a[k1];
    }
    __builtin_amdgcn_wave_barrier();

    // ---- stage 3: read B'[n0,k0,k1] over n0; p2(64n0+s4) = 68n0 + s4+(s4>>4) ----
    {
        const int s4 = (t >> 3) * 8 + (t & 7);
        const cf* pr3 = &sb[q][s4 + (s4 >> 4)];
        #pragma unroll
        for (int n0 = 0; n0 < 8; ++n0) a[n0] = pr3[68 * n0];
    }
    __builtin_amdgcn_wave_barrier();
    fft8(a);   // a[k2]

    // final write: X[k0 + 8*k1 + 64*k2]; p2(64k2+s5) = 68k2 + s5+(s5>>4)
    {
        const int s5 = (t >> 3) + 8 * (t & 7);
        cf* pw3 = &sb[q][s5 + (s5 >> 4)];
        #pragma unroll
        for (int k2 = 0; k2 < 8; ++k2) pw3[68 * k2] = a[k2];
    }
    __syncthreads();   // cross-wave: spectra visible to all waves

    // ---- comb pilot LS: pil[tt][rr][k] = Y_l[rr][tt+2k] / x_ls[tt][tt+2k] ----
    float4 pout[2];   // [j] -> packed {rr0.re, rr0.im, rr1.re, rr1.im}
    #pragma unroll
    for (int j = 0; j < 2; ++j) {
        int comb = j + 2 * tid;
        int pc = p2(comb);
        cf y0l = sb[2][pc];
        cf y1l = sb[3][pc];
        pout[j] = make_float4((y0l.x * pxr[j] + y0l.y * pxi[j]) * pinv[j],
                              (y0l.y * pxr[j] - y0l.x * pxi[j]) * pinv[j],
                              (y1l.x * pxr[j] + y1l.y * pxi[j]) * pinv[j],
                              (y1l.y * pxr[j] - y1l.x * pxi[j]) * pinv[j]);
    }
    __syncthreads();   // all LS-spectra reads done before in-place overwrite
    {
        float4* pilA = (float4*)sb[2];   // tt = 0
        float4* pilB = (float4*)sb[3];   // tt = 1
        pilA[p4(tid)] = pout[0];
        pilB[p4(tid)] = pout[1];
    }
    __syncthreads();

    // ---- pair-of-subcarriers solve: thread T owns n = 2T and n = 2T+1 ----
    {
        const float4* pilA = (const float4*)sb[2];
        const float4* pilB = (const float4*)sb[3];
        const int T  = tid;
        const int Tp = (T + 1 < 256) ? T + 1 : 255;
        const int Tm = (T - 1 > 0) ? T - 1 : 0;

        float4 A0 = pilA[p4(T)];
        float4 A1 = pilA[p4(Tp)];
        float4 Bm = pilB[p4(Tm)];
        float4 B0 = pilB[p4(T)];

        // Y at adjacent padded slots: p2(2T+1) == p2(2T)+1
        const int yb = 2 * T + (T >> 3);
        cf Y0e = sb[0][yb], Y0o = sb[0][yb + 1];
        cf Y1e = sb[1][yb], Y1o = sb[1][yb + 1];

        // H[rr][tt]: pilX = {rr0.re, rr0.im, rr1.re, rr1.im}
        // even n=2T : t0 exact = A0       ; t1 = avg(Bm, B0)
        // odd  n=2T+1: t0 = avg(A0, A1)   ; t1 exact = B0
        cf H00e = {A0.x, A0.y}, H10e = {A0.z, A0.w};
        cf H01e = {0.5f * (Bm.x + B0.x), 0.5f * (Bm.y + B0.y)};
        cf H11e = {0.5f * (Bm.z + B0.z), 0.5f * (Bm.w + B0.w)};
        cf H00o = {0.5f * (A0.x + A1.x), 0.5f * (A0.y + A1.y)};
        cf H10o = {0.5f * (A0.z + A1.z), 0.5f * (A0.w + A1.w)};
        cf H01o = {B0.x, B0.y}, H11o = {B0.z, B0.w};

        const float bnd = 0.63245553203367587f; // 2/sqrt(10)
        const size_t bbase = (size_t)B * 2048;
        float* xop = out + (size_t)b * 2048 + (size_t)T * 8;
        float* b0p = out + bbase + ((size_t)b * 2 + 0) * 2048 + (size_t)T * 8;
        float* b1p = out + bbase + ((size_t)b * 2 + 1) * 2048 + (size_t)T * 8;

        auto bits2 = [&](float v, float& m0, float& m1) {
            bool gt0 = v > 0.0f;
            bool hi  = gt0 ? (v > bnd) : (v > -bnd);
            m1 = gt0 ? 1.0f : 0.0f;
            m0 = hi  ? 1.0f : 0.0f;
        };

        auto solve_store = [&](cf H00, cf H01, cf H10, cf H11, cf Y0, cf Y1, int half) {
            cf det  = csub(cmul(H00, H11), cmul(H01, H10));
            cf num0 = csub(cmul(H11, Y0), cmul(H01, Y1));
            cf num1 = csub(cmul(H00, Y1), cmul(H10, Y0));
            float invden = 1.0f / (det.x * det.x + det.y * det.y);
            float X0r = (num0.x * det.x + num0.y * det.y) * invden;
            float X0i = (num0.y * det.x - num0.x * det.y) * invden;
            float X1r = (num1.x * det.x + num1.y * det.y) * invden;
            float X1i = (num1.y * det.x - num1.x * det.y) * invden;

            *(float4*)(xop + 4 * half) = make_float4(X0r, X0i, X1r, X1i);

            float a0, a1, a2, a3;
            bits2(X0r, a0, a1); bits2(X0i, a2, a3);
            *(float4*)(b0p + 4 * half) = make_float4(a0, a1, a2, a3);
            bits2(X1r, a0, a1); bits2(X1i, a2, a3);
            *(float4*)(b1p + 4 * half) = make_float4(a0, a1, a2, a3);
        };

        solve_store(H00e, H01e, H10e, H11e, Y0e, Y1e, 0);
        solve_store(H00o, H01o, H10o, H11o, Y0o, Y1o, 1);
    }
}

} // namespace

extern "C" void kernel_launch(void* const* d_in, const int* in_sizes, int n_in,
                              void* d_out, int out_size, void* d_ws, size_t ws_size,
                              hipStream_t stream) {
    const float* y_data = (const float*)d_in[0];
    const float* y_ls   = (const float*)d_in[1];
    const int*   x_idx  = (const int*)d_in[2];
    float* out = (float*)d_out;

    int B = in_sizes[0] / (2 * NTOT * 2);   // batch from flat input size
    ofdm_mimo_kernel<<<B, 256, 0, stream>>>(y_data, y_ls, x_idx, out, B);
}